// Round 4
// baseline (247.726 us; speedup 1.0000x reference)
//
#include <hip/hip_runtime.h>

// Problem constants
#define BB 2
#define SQ 2048
#define SK 2048
#define DD 1024
#define HH 16
#define HS 64
#define SCALE 0.125f
#define LOG2E 1.4426950408889634f

typedef __bf16 bf16x8 __attribute__((ext_vector_type(8)));
typedef float f32x4 __attribute__((ext_vector_type(4)));
typedef unsigned int uint;

__device__ __forceinline__ void gload_lds16(const __bf16* g, __bf16* l) {
    __builtin_amdgcn_global_load_lds((const __attribute__((address_space(1))) uint*)(g),
                                     (__attribute__((address_space(3))) uint*)(l), 16, 0, 0);
}

// ---------------- cast fp32 -> bf16 (both inputs in one launch) ----------------
__global__ void cast2_f32_bf16(const float* __restrict__ in0, const float* __restrict__ in1,
                               __bf16* __restrict__ out0, __bf16* __restrict__ out1, int n8each) {
    int i = blockIdx.x * blockDim.x + threadIdx.x;
    const float* src;
    __bf16* dst;
    int j;
    if (i < n8each) { src = in0; dst = out0; j = i; }
    else            { src = in1; dst = out1; j = i - n8each; }
    const float4* p = ((const float4*)src) + (size_t)j * 2;
    float4 a = p[0], b = p[1];
    bf16x8 v = {(__bf16)a.x, (__bf16)a.y, (__bf16)a.z, (__bf16)a.w,
                (__bf16)b.x, (__bf16)b.y, (__bf16)b.z, (__bf16)b.w};
    ((bf16x8*)dst)[j] = v;
}

// ------------- cast+transpose the 4 weight matrices [K][N] -> bf16 [N][K] -------------
__global__ void wtrans(const float* __restrict__ W0, const float* __restrict__ W1,
                       const float* __restrict__ W2, const float* __restrict__ W3,
                       __bf16* __restrict__ Wt) {
    __shared__ __bf16 tile[32][33];
    const float* W = blockIdx.z == 0 ? W0 : blockIdx.z == 1 ? W1 : blockIdx.z == 2 ? W2 : W3;
    __bf16* out = Wt + (size_t)blockIdx.z * DD * DD;
    int tx = threadIdx.x, ty = threadIdx.y;     // (32, 8)
    int k0 = blockIdx.y * 32, n0 = blockIdx.x * 32;
#pragma unroll
    for (int j = 0; j < 4; ++j)
        tile[ty + j * 8][tx] = (__bf16)W[(size_t)(k0 + ty + j * 8) * DD + n0 + tx];
    __syncthreads();
#pragma unroll
    for (int j = 0; j < 4; ++j)
        out[(size_t)(n0 + ty + j * 8) * DD + k0 + tx] = tile[tx][ty + j * 8];
}

// ------------- GEMM body: acc = A[4096,1024] @ Bt[1024,1024]^T -------------
// 128x128 tile, BK=64, 256 threads (4 waves, 64x64 quadrant each), global_load_lds staging
// MODE 0: C = bf16 (acc+bias)*scale ; MODE 1: C = float acc+bias ; MODE 2: transposed Vt write
#define BM 128
#define BN 128
#define BK 64
template <int MODE>
__device__ __forceinline__ void gemm_body(const __bf16* __restrict__ A, const __bf16* __restrict__ Bt,
                                          const float* __restrict__ bias, void* __restrict__ Cout,
                                          float scale) {
    __shared__ __bf16 As[BM][BK];
    __shared__ __bf16 Bs[BN][BK];
    int t = threadIdx.x;
    int w = t >> 6, l = t & 63;
    int lm = l & 15, lk = l >> 4;
    int wr = w >> 1, wc = w & 1;
    int br = blockIdx.y, bc = blockIdx.x;
    int srow = (l >> 3), scol = (l & 7) * 8;
    f32x4 acc[4][4] = {};
    for (int kt = 0; kt < 1024; kt += BK) {
        __syncthreads();
#pragma unroll
        for (int j = 0; j < 4; ++j) {
            int r0 = (w * 4 + j) * 8;
            gload_lds16(&A[(size_t)(br * BM + r0 + srow) * 1024 + kt + scol], &As[r0][0]);
            gload_lds16(&Bt[(size_t)(bc * BN + r0 + srow) * 1024 + kt + scol], &Bs[r0][0]);
        }
        __syncthreads();
#pragma unroll
        for (int kk = 0; kk < BK; kk += 32) {
            bf16x8 af[4], bf[4];
#pragma unroll
            for (int m = 0; m < 4; ++m) af[m] = *(const bf16x8*)&As[wr * 64 + m * 16 + lm][kk + lk * 8];
#pragma unroll
            for (int n = 0; n < 4; ++n) bf[n] = *(const bf16x8*)&Bs[wc * 64 + n * 16 + lm][kk + lk * 8];
#pragma unroll
            for (int m = 0; m < 4; ++m)
#pragma unroll
                for (int n = 0; n < 4; ++n)
                    acc[m][n] = __builtin_amdgcn_mfma_f32_16x16x32_bf16(af[m], bf[n], acc[m][n], 0, 0, 0);
        }
    }
#pragma unroll
    for (int m = 0; m < 4; ++m)
#pragma unroll
        for (int n = 0; n < 4; ++n) {
            int col = bc * BN + wc * 64 + n * 16 + lm;
            float bv = bias[col];
            if constexpr (MODE == 2) {
                // Vt[((b*16+h)*64+d)*2048 + sk], sk = global row; 4 accs are 4 consecutive sk
                int row = br * BM + wr * 64 + m * 16 + lk * 4;   // sk0 (multiple of 4)
                int b_ = row >> 11, sk = row & 2047;
                int h_ = col >> 6, d_ = col & 63;
                union { ushort4 u; __bf16 h[4]; } pk;
#pragma unroll
                for (int r = 0; r < 4; ++r) pk.h[r] = (__bf16)(acc[m][n][r] + bv);
                *(ushort4*)((__bf16*)Cout + ((size_t)((b_ * 16 + h_) * 64 + d_) * 2048 + sk)) = pk.u;
            } else {
#pragma unroll
                for (int r = 0; r < 4; ++r) {
                    int row = br * BM + wr * 64 + m * 16 + lk * 4 + r;
                    if constexpr (MODE == 0)
                        ((__bf16*)Cout)[(size_t)row * 1024 + col] = (__bf16)((acc[m][n][r] + bv) * scale);
                    else
                        ((float*)Cout)[(size_t)row * 1024 + col] = acc[m][n][r] + bv;
                }
            }
        }
}

// fused Q/K/V projections: z==0 -> Q (scaled), z==1 -> K, z==2 -> V written transposed as Vt
__global__ __launch_bounds__(256) void gemm_qkv(const __bf16* __restrict__ Ain, const __bf16* __restrict__ Actx,
                                                const __bf16* __restrict__ Wt,
                                                const float* __restrict__ bq, const float* __restrict__ bk,
                                                const float* __restrict__ bv,
                                                __bf16* __restrict__ Qb, __bf16* __restrict__ Kb,
                                                __bf16* __restrict__ Vtb, float qscale) {
    int z = blockIdx.z;
    const __bf16* A = (z == 0) ? Ain : Actx;
    const __bf16* B = Wt + (size_t)z * DD * DD;
    if (z == 0)      gemm_body<0>(A, B, bq, Qb, qscale);
    else if (z == 1) gemm_body<0>(A, B, bk, Kb, 1.f);
    else             gemm_body<2>(A, B, bv, Vtb, 1.f);
}

__global__ __launch_bounds__(256) void gemm_out(const __bf16* __restrict__ A, const __bf16* __restrict__ Bt,
                                                const float* __restrict__ bias, float* __restrict__ C) {
    gemm_body<1>(A, Bt, bias, C, 1.f);
}

// ------------- flash attention, no-max softmax (Q pre-scaled by SCALE*LOG2E) -------------
// 2 waves/block, 32 q-rows per wave (2 m-frags), KV tiles of 64; deferred row-sum.
// K/V LDS: linear [64][64] with 16B-chunk XOR swizzle (chunk ^= row&7) -> conflict-free
// T14: next tile's global loads issued before current tile's compute, LDS write after barrier
// T5: setprio(1) around MFMA clusters
__global__ __launch_bounds__(128) void flash_attn(const __bf16* __restrict__ Q,
                                                  const __bf16* __restrict__ Kb,
                                                  const __bf16* __restrict__ Vt,
                                                  __bf16* __restrict__ O) {
    __shared__ __bf16 Ks[64 * 64];
    __shared__ __bf16 Vs[64 * 64];   // Vt tile: [d][kv]
    __shared__ __bf16 Ps[2][32][72];
    int t = threadIdx.x, w = t >> 6, l = t & 63;
    int lm = l & 15, lk = l >> 4;
    int bh = blockIdx.y, b = bh >> 4, h = bh & 15;
    int q0 = blockIdx.x * 64;

    // Q fragments straight from global (one-time): wave w owns q rows q0+w*32 .. +31
    bf16x8 qf[2][2];
#pragma unroll
    for (int m = 0; m < 2; ++m)
#pragma unroll
        for (int kk = 0; kk < 2; ++kk)
            qf[m][kk] = *(const bf16x8*)&Q[(size_t)(b * SQ + q0 + w * 32 + m * 16 + lm) * DD + h * HS + kk * 32 + lk * 8];

    // staging geometry: 128 threads cover 64x64 tile in 4 row-strides of 16
    int r0 = t >> 3, c8 = t & 7;
    int chs = c8 ^ (r0 & 7);           // (r0+16j)&7 == r0&7
    const __bf16* kbase = Kb + (size_t)b * SK * DD + h * HS;
    const __bf16* vbase = Vt + (size_t)bh * HS * SK;

    float4 kr[4], vr[4];
#define FA_LOAD(KV)                                                                   \
    _Pragma("unroll")                                                                 \
    for (int j = 0; j < 4; ++j) {                                                     \
        kr[j] = *(const float4*)&kbase[(size_t)((KV) + r0 + 16 * j) * DD + c8 * 8];   \
        vr[j] = *(const float4*)&vbase[(size_t)(r0 + 16 * j) * SK + (KV) + c8 * 8];   \
    }
#define FA_WRITE()                                                                    \
    _Pragma("unroll")                                                                 \
    for (int j = 0; j < 4; ++j) {                                                     \
        *(float4*)&Ks[(r0 + 16 * j) * 64 + chs * 8] = kr[j];                          \
        *(float4*)&Vs[(r0 + 16 * j) * 64 + chs * 8] = vr[j];                          \
    }

    FA_LOAD(0);
    FA_WRITE();
    __syncthreads();

    f32x4 o[2][4] = {};
    float lsum[2][4] = {};

    for (int kv0 = 0; kv0 < SK; kv0 += 64) {
        if (kv0 + 64 < SK) { FA_LOAD(kv0 + 64); }   // issue early; latency hides under compute

        // S = Q K^T   (rows: q = m*16 + lk*4+r within wave tile; cols: kv = n*16+lm)
        f32x4 s[2][4] = {};
        __builtin_amdgcn_s_setprio(1);
#pragma unroll
        for (int kk = 0; kk < 2; ++kk) {
            bf16x8 kf[4];
#pragma unroll
            for (int n = 0; n < 4; ++n)
                kf[n] = *(const bf16x8*)&Ks[(n * 16 + lm) * 64 + (((kk * 4 + lk) ^ (lm & 7)) * 8)];
#pragma unroll
            for (int m = 0; m < 2; ++m)
#pragma unroll
                for (int n = 0; n < 4; ++n)
                    s[m][n] = __builtin_amdgcn_mfma_f32_16x16x32_bf16(qf[m][kk], kf[n], s[m][n], 0, 0, 0);
        }
        __builtin_amdgcn_s_setprio(0);

        // P = exp2(S); accumulate per-lane row partial sums; write P to per-wave LDS
#pragma unroll
        for (int m = 0; m < 2; ++m)
#pragma unroll
            for (int n = 0; n < 4; ++n)
#pragma unroll
                for (int r = 0; r < 4; ++r) {
                    float p = exp2f(s[m][n][r]);
                    lsum[m][r] += p;
                    Ps[w][m * 16 + lk * 4 + r][n * 16 + lm] = (__bf16)p;
                }

        // O += P V   (A = P[32 q][64 kv], B^T = Vs[d][kv]); vf shared across m
        __builtin_amdgcn_s_setprio(1);
#pragma unroll
        for (int kk = 0; kk < 2; ++kk) {
            bf16x8 pf[2], vf[4];
#pragma unroll
            for (int m = 0; m < 2; ++m) pf[m] = *(const bf16x8*)&Ps[w][m * 16 + lm][kk * 32 + lk * 8];
#pragma unroll
            for (int dn = 0; dn < 4; ++dn)
                vf[dn] = *(const bf16x8*)&Vs[(dn * 16 + lm) * 64 + (((kk * 4 + lk) ^ (lm & 7)) * 8)];
#pragma unroll
            for (int m = 0; m < 2; ++m)
#pragma unroll
                for (int dn = 0; dn < 4; ++dn)
                    o[m][dn] = __builtin_amdgcn_mfma_f32_16x16x32_bf16(pf[m], vf[dn], o[m][dn], 0, 0, 0);
        }
        __builtin_amdgcn_s_setprio(0);

        __syncthreads();                       // all waves done reading K/V LDS
        if (kv0 + 64 < SK) {
            FA_WRITE();                        // land next tile
            __syncthreads();
        }
    }

    // deferred reduction of row sums over the 16-lane lm group
#pragma unroll
    for (int m = 0; m < 2; ++m)
#pragma unroll
        for (int r = 0; r < 4; ++r) {
#pragma unroll
            for (int msk = 1; msk < 16; msk <<= 1) lsum[m][r] += __shfl_xor(lsum[m][r], msk);
            lsum[m][r] = 1.f / lsum[m][r];
        }
#pragma unroll
    for (int m = 0; m < 2; ++m)
#pragma unroll
        for (int dn = 0; dn < 4; ++dn)
#pragma unroll
            for (int r = 0; r < 4; ++r) {
                int row = q0 + w * 32 + m * 16 + lk * 4 + r;
                int col = h * HS + dn * 16 + lm;
                O[(size_t)(b * SQ + row) * DD + col] = (__bf16)(o[m][dn][r] * lsum[m][r]);
            }
}

extern "C" void kernel_launch(void* const* d_in, const int* in_sizes, int n_in,
                              void* d_out, int out_size, void* d_ws, size_t ws_size,
                              hipStream_t stream) {
    const float* inputs  = (const float*)d_in[0];
    const float* context = (const float*)d_in[1];
    const float* Wq = (const float*)d_in[2];
    const float* bq = (const float*)d_in[3];
    const float* Wk = (const float*)d_in[4];
    const float* bk = (const float*)d_in[5];
    const float* Wv = (const float*)d_in[6];
    const float* bv = (const float*)d_in[7];
    const float* Wo = (const float*)d_in[8];
    const float* bo = (const float*)d_in[9];
    float* out = (float*)d_out;

    char* ws = (char*)d_ws;
    const size_t SEG = (size_t)4096 * 1024 * sizeof(__bf16);  // 8 MB
    __bf16* inA  = (__bf16*)(ws + 0 * SEG);
    __bf16* ctxB = (__bf16*)(ws + 1 * SEG);
    __bf16* Wt   = (__bf16*)(ws + 2 * SEG);   // 4 x 1024x1024 bf16
    __bf16* Qb   = (__bf16*)(ws + 3 * SEG);
    __bf16* Kbuf = (__bf16*)(ws + 4 * SEG);
    __bf16* Vtb  = (__bf16*)(ws + 5 * SEG);   // V written directly transposed by gemm_qkv
    __bf16* attb = ctxB;                      // context_bf16 dead after QKV GEMM

    int n8 = 4096 * 1024 / 8;
    cast2_f32_bf16<<<2 * n8 / 256, 256, 0, stream>>>(inputs, context, inA, ctxB, n8);
    wtrans<<<dim3(32, 32, 4), dim3(32, 8), 0, stream>>>(Wq, Wk, Wv, Wo, Wt);

    gemm_qkv<<<dim3(8, 32, 3), 256, 0, stream>>>(inA, ctxB, Wt, bq, bk, bv,
                                                 Qb, Kbuf, Vtb, SCALE * LOG2E);

    flash_attn<<<dim3(32, 32), 128, 0, stream>>>(Qb, Kbuf, Vtb, attb);

    gemm_out<<<dim3(8, 32), 256, 0, stream>>>(attb, Wt + (size_t)3 * DD * DD, bo, out);
}

// Round 5
// 172.297 us; speedup vs baseline: 1.4378x; 1.4378x over previous
//
#include <hip/hip_runtime.h>

// Problem constants
#define BB 2
#define SQ 2048
#define SK 2048
#define DD 1024
#define HH 16
#define HS 64
#define SCALE 0.125f
#define LOG2E 1.4426950408889634f

typedef __bf16 bf16x8 __attribute__((ext_vector_type(8)));
typedef float f32x4 __attribute__((ext_vector_type(4)));
typedef unsigned int uint;

__device__ __forceinline__ void gload_lds16(const __bf16* g, __bf16* l) {
    __builtin_amdgcn_global_load_lds((const __attribute__((address_space(1))) uint*)(g),
                                     (__attribute__((address_space(3))) uint*)(l), 16, 0, 0);
}

// ---------------- cast fp32 -> bf16 (both inputs in one launch) ----------------
__global__ void cast2_f32_bf16(const float* __restrict__ in0, const float* __restrict__ in1,
                               __bf16* __restrict__ out0, __bf16* __restrict__ out1, int n8each) {
    int i = blockIdx.x * blockDim.x + threadIdx.x;
    const float* src;
    __bf16* dst;
    int j;
    if (i < n8each) { src = in0; dst = out0; j = i; }
    else            { src = in1; dst = out1; j = i - n8each; }
    const float4* p = ((const float4*)src) + (size_t)j * 2;
    float4 a = p[0], b = p[1];
    bf16x8 v = {(__bf16)a.x, (__bf16)a.y, (__bf16)a.z, (__bf16)a.w,
                (__bf16)b.x, (__bf16)b.y, (__bf16)b.z, (__bf16)b.w};
    ((bf16x8*)dst)[j] = v;
}

// ------------- cast+transpose the 4 weight matrices [K][N] -> bf16 [N][K] -------------
__global__ void wtrans(const float* __restrict__ W0, const float* __restrict__ W1,
                       const float* __restrict__ W2, const float* __restrict__ W3,
                       __bf16* __restrict__ Wt) {
    __shared__ __bf16 tile[32][33];
    const float* W = blockIdx.z == 0 ? W0 : blockIdx.z == 1 ? W1 : blockIdx.z == 2 ? W2 : W3;
    __bf16* out = Wt + (size_t)blockIdx.z * DD * DD;
    int tx = threadIdx.x, ty = threadIdx.y;     // (32, 8)
    int k0 = blockIdx.y * 32, n0 = blockIdx.x * 32;
#pragma unroll
    for (int j = 0; j < 4; ++j)
        tile[ty + j * 8][tx] = (__bf16)W[(size_t)(k0 + ty + j * 8) * DD + n0 + tx];
    __syncthreads();
#pragma unroll
    for (int j = 0; j < 4; ++j)
        out[(size_t)(n0 + ty + j * 8) * DD + k0 + tx] = tile[tx][ty + j * 8];
}

// ------------- GEMM body: acc = A[4096,1024] @ Bt[1024,1024]^T -------------
// 128x128 tile, BK=64, 256 threads (4 waves, 64x64 quadrant each), global_load_lds staging
// MODE 0: C = bf16 (acc+bias)*scale ; MODE 1: C = float acc+bias ; MODE 2: transposed Vt write
#define BM 128
#define BN 128
#define BK 64
template <int MODE>
__device__ __forceinline__ void gemm_body(const __bf16* __restrict__ A, const __bf16* __restrict__ Bt,
                                          const float* __restrict__ bias, void* __restrict__ Cout,
                                          float scale) {
    __shared__ __bf16 As[BM][BK];
    __shared__ __bf16 Bs[BN][BK];
    int t = threadIdx.x;
    int w = t >> 6, l = t & 63;
    int lm = l & 15, lk = l >> 4;
    int wr = w >> 1, wc = w & 1;
    int br = blockIdx.y, bc = blockIdx.x;
    int srow = (l >> 3), scol = (l & 7) * 8;
    f32x4 acc[4][4] = {};
    for (int kt = 0; kt < 1024; kt += BK) {
        __syncthreads();
#pragma unroll
        for (int j = 0; j < 4; ++j) {
            int r0 = (w * 4 + j) * 8;
            gload_lds16(&A[(size_t)(br * BM + r0 + srow) * 1024 + kt + scol], &As[r0][0]);
            gload_lds16(&Bt[(size_t)(bc * BN + r0 + srow) * 1024 + kt + scol], &Bs[r0][0]);
        }
        __syncthreads();
#pragma unroll
        for (int kk = 0; kk < BK; kk += 32) {
            bf16x8 af[4], bf[4];
#pragma unroll
            for (int m = 0; m < 4; ++m) af[m] = *(const bf16x8*)&As[wr * 64 + m * 16 + lm][kk + lk * 8];
#pragma unroll
            for (int n = 0; n < 4; ++n) bf[n] = *(const bf16x8*)&Bs[wc * 64 + n * 16 + lm][kk + lk * 8];
#pragma unroll
            for (int m = 0; m < 4; ++m)
#pragma unroll
                for (int n = 0; n < 4; ++n)
                    acc[m][n] = __builtin_amdgcn_mfma_f32_16x16x32_bf16(af[m], bf[n], acc[m][n], 0, 0, 0);
        }
    }
#pragma unroll
    for (int m = 0; m < 4; ++m)
#pragma unroll
        for (int n = 0; n < 4; ++n) {
            int col = bc * BN + wc * 64 + n * 16 + lm;
            float bv = bias[col];
            if constexpr (MODE == 2) {
                // Vt[((b*16+h)*64+d)*2048 + sk], sk = global row; 4 accs are 4 consecutive sk
                int row = br * BM + wr * 64 + m * 16 + lk * 4;   // sk0 (multiple of 4)
                int b_ = row >> 11, sk = row & 2047;
                int h_ = col >> 6, d_ = col & 63;
                union { ushort4 u; __bf16 h[4]; } pk;
#pragma unroll
                for (int r = 0; r < 4; ++r) pk.h[r] = (__bf16)(acc[m][n][r] + bv);
                *(ushort4*)((__bf16*)Cout + ((size_t)((b_ * 16 + h_) * 64 + d_) * 2048 + sk)) = pk.u;
            } else {
#pragma unroll
                for (int r = 0; r < 4; ++r) {
                    int row = br * BM + wr * 64 + m * 16 + lk * 4 + r;
                    if constexpr (MODE == 0)
                        ((__bf16*)Cout)[(size_t)row * 1024 + col] = (__bf16)((acc[m][n][r] + bv) * scale);
                    else
                        ((float*)Cout)[(size_t)row * 1024 + col] = acc[m][n][r] + bv;
                }
            }
        }
}

// fused Q/K/V projections: z==0 -> Q (scaled), z==1 -> K, z==2 -> V written transposed as Vt
__global__ __launch_bounds__(256) void gemm_qkv(const __bf16* __restrict__ Ain, const __bf16* __restrict__ Actx,
                                                const __bf16* __restrict__ Wt,
                                                const float* __restrict__ bq, const float* __restrict__ bk,
                                                const float* __restrict__ bv,
                                                __bf16* __restrict__ Qb, __bf16* __restrict__ Kb,
                                                __bf16* __restrict__ Vtb, float qscale) {
    int z = blockIdx.z;
    const __bf16* A = (z == 0) ? Ain : Actx;
    const __bf16* B = Wt + (size_t)z * DD * DD;
    if (z == 0)      gemm_body<0>(A, B, bq, Qb, qscale);
    else if (z == 1) gemm_body<0>(A, B, bk, Kb, 1.f);
    else             gemm_body<2>(A, B, bv, Vtb, 1.f);
}

__global__ __launch_bounds__(256) void gemm_out(const __bf16* __restrict__ A, const __bf16* __restrict__ Bt,
                                                const float* __restrict__ bias, float* __restrict__ C) {
    gemm_body<1>(A, Bt, bias, C, 1.f);
}

// ------------- flash attention, no-max softmax (Q pre-scaled by SCALE*LOG2E) -------------
// QBLK=128: 4 waves x 32 q-rows (2 m-frags each); KV tiles of 64; deferred row-sum.
// K/V LDS: linear [64][64] with 16B-chunk XOR swizzle (chunk ^= row&7) -> conflict-free
// T14: next tile's loads in NAMED float4 regs (arrays spill! round-4 lesson), write after barrier
// T5: setprio(1) around MFMA clusters
__global__ __launch_bounds__(256) void flash_attn(const __bf16* __restrict__ Q,
                                                  const __bf16* __restrict__ Kb,
                                                  const __bf16* __restrict__ Vt,
                                                  __bf16* __restrict__ O) {
    __shared__ __bf16 Ks[64 * 64];
    __shared__ __bf16 Vs[64 * 64];   // Vt tile: [d][kv]
    __shared__ __bf16 Ps[4][32][72];
    int t = threadIdx.x, w = t >> 6, l = t & 63;
    int lm = l & 15, lk = l >> 4;
    int bh = blockIdx.y, b = bh >> 4, h = bh & 15;
    int q0 = blockIdx.x * 128;

    // Q fragments straight from global (one-time): wave w owns q rows q0+w*32 .. +31
    bf16x8 qf[2][2];
#pragma unroll
    for (int m = 0; m < 2; ++m)
#pragma unroll
        for (int kk = 0; kk < 2; ++kk)
            qf[m][kk] = *(const bf16x8*)&Q[(size_t)(b * SQ + q0 + w * 32 + m * 16 + lm) * DD + h * HS + kk * 32 + lk * 8];

    // staging geometry: thread covers (r0, c8) and (r0+32, c8); swizzled chunk = c8 ^ (r0&7)
    int r0 = t >> 3, c8 = t & 7;
    int chs = c8 ^ (r0 & 7);
    const __bf16* kbase = Kb + (size_t)b * SK * DD + h * HS;      // + (kv+row)*DD + c8*8
    const __bf16* vbase = Vt + (size_t)bh * HS * SK;              // + d*SK + kv + c8*8
    __bf16* ksl0 = &Ks[(r0)      * 64 + chs * 8];
    __bf16* ksl1 = &Ks[(r0 + 32) * 64 + chs * 8];
    __bf16* vsl0 = &Vs[(r0)      * 64 + chs * 8];
    __bf16* vsl1 = &Vs[(r0 + 32) * 64 + chs * 8];

    float4 kr0, kr1, vr0, vr1;   // NAMED regs only (arrays -> scratch, round-4 lesson)
#define FA_LOAD(KV)                                                              \
    kr0 = *(const float4*)&kbase[(size_t)((KV) + r0) * DD + c8 * 8];             \
    kr1 = *(const float4*)&kbase[(size_t)((KV) + r0 + 32) * DD + c8 * 8];        \
    vr0 = *(const float4*)&vbase[(size_t)(r0) * SK + (KV) + c8 * 8];             \
    vr1 = *(const float4*)&vbase[(size_t)(r0 + 32) * SK + (KV) + c8 * 8];
#define FA_WRITE()                                                               \
    *(float4*)ksl0 = kr0; *(float4*)ksl1 = kr1;                                  \
    *(float4*)vsl0 = vr0; *(float4*)vsl1 = vr1;

    FA_LOAD(0);
    FA_WRITE();
    __syncthreads();

    f32x4 o[2][4] = {};
    float lsum[2][4] = {};

    for (int kv0 = 0; kv0 < SK; kv0 += 64) {
        if (kv0 + 64 < SK) { FA_LOAD(kv0 + 64); }   // issue early; latency hides under compute

        // S = Q K^T   (rows: q = m*16 + lk*4+r within wave tile; cols: kv = n*16+lm)
        f32x4 s[2][4] = {};
        __builtin_amdgcn_s_setprio(1);
#pragma unroll
        for (int kk = 0; kk < 2; ++kk) {
            bf16x8 kf[4];
#pragma unroll
            for (int n = 0; n < 4; ++n)
                kf[n] = *(const bf16x8*)&Ks[(n * 16 + lm) * 64 + (((kk * 4 + lk) ^ (lm & 7)) * 8)];
#pragma unroll
            for (int m = 0; m < 2; ++m)
#pragma unroll
                for (int n = 0; n < 4; ++n)
                    s[m][n] = __builtin_amdgcn_mfma_f32_16x16x32_bf16(qf[m][kk], kf[n], s[m][n], 0, 0, 0);
        }
        __builtin_amdgcn_s_setprio(0);

        // P = exp2(S); accumulate per-lane row partial sums; write P to per-wave LDS
#pragma unroll
        for (int m = 0; m < 2; ++m)
#pragma unroll
            for (int n = 0; n < 4; ++n)
#pragma unroll
                for (int r = 0; r < 4; ++r) {
                    float p = exp2f(s[m][n][r]);
                    lsum[m][r] += p;
                    Ps[w][m * 16 + lk * 4 + r][n * 16 + lm] = (__bf16)p;
                }

        // O += P V   (A = P[32 q][64 kv], B^T = Vs[d][kv]); vf shared across m
        __builtin_amdgcn_s_setprio(1);
#pragma unroll
        for (int kk = 0; kk < 2; ++kk) {
            bf16x8 pf[2], vf[4];
#pragma unroll
            for (int m = 0; m < 2; ++m) pf[m] = *(const bf16x8*)&Ps[w][m * 16 + lm][kk * 32 + lk * 8];
#pragma unroll
            for (int dn = 0; dn < 4; ++dn)
                vf[dn] = *(const bf16x8*)&Vs[(dn * 16 + lm) * 64 + (((kk * 4 + lk) ^ (lm & 7)) * 8)];
#pragma unroll
            for (int m = 0; m < 2; ++m)
#pragma unroll
                for (int dn = 0; dn < 4; ++dn)
                    o[m][dn] = __builtin_amdgcn_mfma_f32_16x16x32_bf16(pf[m], vf[dn], o[m][dn], 0, 0, 0);
        }
        __builtin_amdgcn_s_setprio(0);

        __syncthreads();                       // all waves done reading K/V LDS
        if (kv0 + 64 < SK) {
            FA_WRITE();                        // land next tile
            __syncthreads();
        }
    }

    // deferred reduction of row sums over the 16-lane lm group
#pragma unroll
    for (int m = 0; m < 2; ++m)
#pragma unroll
        for (int r = 0; r < 4; ++r) {
#pragma unroll
            for (int msk = 1; msk < 16; msk <<= 1) lsum[m][r] += __shfl_xor(lsum[m][r], msk);
            lsum[m][r] = 1.f / lsum[m][r];
        }
#pragma unroll
    for (int m = 0; m < 2; ++m)
#pragma unroll
        for (int dn = 0; dn < 4; ++dn)
#pragma unroll
            for (int r = 0; r < 4; ++r) {
                int row = q0 + w * 32 + m * 16 + lk * 4 + r;
                int col = h * HS + dn * 16 + lm;
                O[(size_t)(b * SQ + row) * DD + col] = (__bf16)(o[m][dn][r] * lsum[m][r]);
            }
}

extern "C" void kernel_launch(void* const* d_in, const int* in_sizes, int n_in,
                              void* d_out, int out_size, void* d_ws, size_t ws_size,
                              hipStream_t stream) {
    const float* inputs  = (const float*)d_in[0];
    const float* context = (const float*)d_in[1];
    const float* Wq = (const float*)d_in[2];
    const float* bq = (const float*)d_in[3];
    const float* Wk = (const float*)d_in[4];
    const float* bk = (const float*)d_in[5];
    const float* Wv = (const float*)d_in[6];
    const float* bv = (const float*)d_in[7];
    const float* Wo = (const float*)d_in[8];
    const float* bo = (const float*)d_in[9];
    float* out = (float*)d_out;

    char* ws = (char*)d_ws;
    const size_t SEG = (size_t)4096 * 1024 * sizeof(__bf16);  // 8 MB
    __bf16* inA  = (__bf16*)(ws + 0 * SEG);
    __bf16* ctxB = (__bf16*)(ws + 1 * SEG);
    __bf16* Wt   = (__bf16*)(ws + 2 * SEG);   // 4 x 1024x1024 bf16
    __bf16* Qb   = (__bf16*)(ws + 3 * SEG);
    __bf16* Kbuf = (__bf16*)(ws + 4 * SEG);
    __bf16* Vtb  = (__bf16*)(ws + 5 * SEG);   // V written directly transposed by gemm_qkv
    __bf16* attb = ctxB;                      // context_bf16 dead after QKV GEMM

    int n8 = 4096 * 1024 / 8;
    cast2_f32_bf16<<<2 * n8 / 256, 256, 0, stream>>>(inputs, context, inA, ctxB, n8);
    wtrans<<<dim3(32, 32, 4), dim3(32, 8), 0, stream>>>(Wq, Wk, Wv, Wo, Wt);

    gemm_qkv<<<dim3(8, 32, 3), 256, 0, stream>>>(inA, ctxB, Wt, bq, bk, bv,
                                                 Qb, Kbuf, Vtb, SCALE * LOG2E);

    flash_attn<<<dim3(16, 32), 256, 0, stream>>>(Qb, Kbuf, Vtb, attb);

    gemm_out<<<dim3(8, 32), 256, 0, stream>>>(attb, Wt + (size_t)3 * DD * DD, bo, out);
}

// Round 6
// 154.964 us; speedup vs baseline: 1.5986x; 1.1118x over previous
//
#include <hip/hip_runtime.h>

// Problem constants
#define BB 2
#define SQ 2048
#define SK 2048
#define DD 1024
#define HH 16
#define HS 64
#define SCALE 0.125f
#define LOG2E 1.4426950408889634f

typedef __bf16 bf16x8 __attribute__((ext_vector_type(8)));
typedef float f32x4 __attribute__((ext_vector_type(4)));
typedef unsigned int uint;

__device__ __forceinline__ void gload_lds16(const __bf16* g, __bf16* l) {
    __builtin_amdgcn_global_load_lds((const __attribute__((address_space(1))) uint*)(g),
                                     (__attribute__((address_space(3))) uint*)(l), 16, 0, 0);
}

// ---------------- cast fp32 -> bf16 (both inputs in one launch) ----------------
__global__ void cast2_f32_bf16(const float* __restrict__ in0, const float* __restrict__ in1,
                               __bf16* __restrict__ out0, __bf16* __restrict__ out1, int n8each) {
    int i = blockIdx.x * blockDim.x + threadIdx.x;
    const float* src;
    __bf16* dst;
    int j;
    if (i < n8each) { src = in0; dst = out0; j = i; }
    else            { src = in1; dst = out1; j = i - n8each; }
    const float4* p = ((const float4*)src) + (size_t)j * 2;
    float4 a = p[0], b = p[1];
    bf16x8 v = {(__bf16)a.x, (__bf16)a.y, (__bf16)a.z, (__bf16)a.w,
                (__bf16)b.x, (__bf16)b.y, (__bf16)b.z, (__bf16)b.w};
    ((bf16x8*)dst)[j] = v;
}

// ------------- cast+transpose the 4 weight matrices [K][N] -> bf16 [N][K] -------------
__global__ void wtrans(const float* __restrict__ W0, const float* __restrict__ W1,
                       const float* __restrict__ W2, const float* __restrict__ W3,
                       __bf16* __restrict__ Wt) {
    __shared__ __bf16 tile[32][33];
    const float* W = blockIdx.z == 0 ? W0 : blockIdx.z == 1 ? W1 : blockIdx.z == 2 ? W2 : W3;
    __bf16* out = Wt + (size_t)blockIdx.z * DD * DD;
    int tx = threadIdx.x, ty = threadIdx.y;     // (32, 8)
    int k0 = blockIdx.y * 32, n0 = blockIdx.x * 32;
#pragma unroll
    for (int j = 0; j < 4; ++j)
        tile[ty + j * 8][tx] = (__bf16)W[(size_t)(k0 + ty + j * 8) * DD + n0 + tx];
    __syncthreads();
#pragma unroll
    for (int j = 0; j < 4; ++j)
        out[(size_t)(n0 + ty + j * 8) * DD + k0 + tx] = tile[tx][ty + j * 8];
}

// ------------- GEMM body: acc = A[4096,1024] @ Bt[1024,1024]^T -------------
// 128x128 tile, BK=64, 256 threads (4 waves, 64x64 quadrant each), global_load_lds staging
// MODE 0: C = bf16 (acc+bias)*scale ; MODE 1: C = float acc+bias ; MODE 2: transposed Vt write
#define BM 128
#define BN 128
#define BK 64
template <int MODE>
__device__ __forceinline__ void gemm_body(const __bf16* __restrict__ A, const __bf16* __restrict__ Bt,
                                          const float* __restrict__ bias, void* __restrict__ Cout,
                                          float scale) {
    __shared__ __bf16 As[BM][BK];
    __shared__ __bf16 Bs[BN][BK];
    int t = threadIdx.x;
    int w = t >> 6, l = t & 63;
    int lm = l & 15, lk = l >> 4;
    int wr = w >> 1, wc = w & 1;
    int br = blockIdx.y, bc = blockIdx.x;
    int srow = (l >> 3), scol = (l & 7) * 8;
    f32x4 acc[4][4] = {};
    for (int kt = 0; kt < 1024; kt += BK) {
        __syncthreads();
#pragma unroll
        for (int j = 0; j < 4; ++j) {
            int r0 = (w * 4 + j) * 8;
            gload_lds16(&A[(size_t)(br * BM + r0 + srow) * 1024 + kt + scol], &As[r0][0]);
            gload_lds16(&Bt[(size_t)(bc * BN + r0 + srow) * 1024 + kt + scol], &Bs[r0][0]);
        }
        __syncthreads();
#pragma unroll
        for (int kk = 0; kk < BK; kk += 32) {
            bf16x8 af[4], bf[4];
#pragma unroll
            for (int m = 0; m < 4; ++m) af[m] = *(const bf16x8*)&As[wr * 64 + m * 16 + lm][kk + lk * 8];
#pragma unroll
            for (int n = 0; n < 4; ++n) bf[n] = *(const bf16x8*)&Bs[wc * 64 + n * 16 + lm][kk + lk * 8];
#pragma unroll
            for (int m = 0; m < 4; ++m)
#pragma unroll
                for (int n = 0; n < 4; ++n)
                    acc[m][n] = __builtin_amdgcn_mfma_f32_16x16x32_bf16(af[m], bf[n], acc[m][n], 0, 0, 0);
        }
    }
#pragma unroll
    for (int m = 0; m < 4; ++m)
#pragma unroll
        for (int n = 0; n < 4; ++n) {
            int col = bc * BN + wc * 64 + n * 16 + lm;
            float bv = bias[col];
            if constexpr (MODE == 2) {
                // Vt[((b*16+h)*64+d)*2048 + sk], sk = global row; 4 accs are 4 consecutive sk
                int row = br * BM + wr * 64 + m * 16 + lk * 4;   // sk0 (multiple of 4)
                int b_ = row >> 11, sk = row & 2047;
                int h_ = col >> 6, d_ = col & 63;
                union { ushort4 u; __bf16 h[4]; } pk;
#pragma unroll
                for (int r = 0; r < 4; ++r) pk.h[r] = (__bf16)(acc[m][n][r] + bv);
                *(ushort4*)((__bf16*)Cout + ((size_t)((b_ * 16 + h_) * 64 + d_) * 2048 + sk)) = pk.u;
            } else {
#pragma unroll
                for (int r = 0; r < 4; ++r) {
                    int row = br * BM + wr * 64 + m * 16 + lk * 4 + r;
                    if constexpr (MODE == 0)
                        ((__bf16*)Cout)[(size_t)row * 1024 + col] = (__bf16)((acc[m][n][r] + bv) * scale);
                    else
                        ((float*)Cout)[(size_t)row * 1024 + col] = acc[m][n][r] + bv;
                }
            }
        }
}

// fused Q/K/V projections: z==0 -> Q (scaled), z==1 -> K, z==2 -> V written transposed as Vt
__global__ __launch_bounds__(256) void gemm_qkv(const __bf16* __restrict__ Ain, const __bf16* __restrict__ Actx,
                                                const __bf16* __restrict__ Wt,
                                                const float* __restrict__ bq, const float* __restrict__ bk,
                                                const float* __restrict__ bv,
                                                __bf16* __restrict__ Qb, __bf16* __restrict__ Kb,
                                                __bf16* __restrict__ Vtb, float qscale) {
    int z = blockIdx.z;
    const __bf16* A = (z == 0) ? Ain : Actx;
    const __bf16* B = Wt + (size_t)z * DD * DD;
    if (z == 0)      gemm_body<0>(A, B, bq, Qb, qscale);
    else if (z == 1) gemm_body<0>(A, B, bk, Kb, 1.f);
    else             gemm_body<2>(A, B, bv, Vtb, 1.f);
}

__global__ __launch_bounds__(256) void gemm_out(const __bf16* __restrict__ A, const __bf16* __restrict__ Bt,
                                                const float* __restrict__ bias, float* __restrict__ C) {
    gemm_body<1>(A, Bt, bias, C, 1.f);
}

// ------------- flash attention, swapped-QK^T (S^T), lane-local P, no P LDS round-trip -------------
// QBLK=128: 4 waves x 32 q-rows (2 m-frags as B-operand); KVBLK=64, double-buffered K/V (1 barrier/tile).
// st[n][m] = mfma(K-frag, Q-frag): lane holds P[q=m*16+lm][kv=16n+4lk+r] -> PV A-frag assembles
// lane-locally under kv-permutation pi; V is staged into LDS pre-permuted by sigma = pi^-1
// (pure kv bit-swap [kk|b|l1|l0|s1|s0] -> [kk|l1|l0|b|s1|s0]).
// K path (staging, swizzle, reads) identical to round-3/5 verified code.
__global__ __launch_bounds__(256) void flash_attn(const __bf16* __restrict__ Q,
                                                  const __bf16* __restrict__ Kb,
                                                  const __bf16* __restrict__ Vt,
                                                  __bf16* __restrict__ O) {
    __shared__ __bf16 Ks[2][64 * 64];
    __shared__ __bf16 Vs[2][64 * 64];
    __shared__ float lsq[4][64];
    int t = threadIdx.x, w = t >> 6, l = t & 63;
    int lm = l & 15, lk = l >> 4;
    int bh = blockIdx.y, b = bh >> 4, h = bh & 15;
    int q0 = blockIdx.x * 128;

    // Q fragments straight from global (one-time): wave w owns q rows q0+w*32 .. +31
    bf16x8 qf[2][2];
#pragma unroll
    for (int m = 0; m < 2; ++m)
#pragma unroll
        for (int kk = 0; kk < 2; ++kk)
            qf[m][kk] = *(const bf16x8*)&Q[(size_t)(b * SQ + q0 + w * 32 + m * 16 + lm) * DD + h * HS + kk * 32 + lk * 8];

    // staging geometry: thread covers rows r0 and r0+32, 8-elem chunk c8
    int r0 = t >> 3, c8 = t & 7;
    int chsK = c8 ^ (r0 & 7);                       // K: 16B-chunk XOR swizzle
    // V permuted-write geometry: float4 covers kv = 8*c8 + u; kappa = kA + (u>>2)*8 + (u&3)
    int kkv = c8 >> 2, bbit = (c8 >> 1) & 1, l1 = c8 & 1;
    int kA = kkv * 32 + l1 * 16 + bbit * 4;
    int cA0 = ((kA >> 3)) ^ (r0 & 7);               // swizzled 16B chunk, half u=0..3
    int cA1 = ((kA >> 3) + 1) ^ (r0 & 7);           // half u=4..7 (kappa+8)
    const __bf16* kbase = Kb + (size_t)b * SK * DD + h * HS;
    const __bf16* vbase = Vt + (size_t)bh * HS * SK;

    float4 kr0, kr1, vr0, vr1;   // NAMED regs only (arrays -> scratch)
#define FA_LOAD(KV)                                                              \
    kr0 = *(const float4*)&kbase[(size_t)((KV) + r0) * DD + c8 * 8];             \
    kr1 = *(const float4*)&kbase[(size_t)((KV) + r0 + 32) * DD + c8 * 8];        \
    vr0 = *(const float4*)&vbase[(size_t)(r0) * SK + (KV) + c8 * 8];             \
    vr1 = *(const float4*)&vbase[(size_t)(r0 + 32) * SK + (KV) + c8 * 8];
#define FA_WRITE(BUF)                                                            \
    *(float4*)&Ks[BUF][(r0) * 64 + chsK * 8] = kr0;                              \
    *(float4*)&Ks[BUF][(r0 + 32) * 64 + chsK * 8] = kr1;                         \
    *(float2*)&Vs[BUF][(r0) * 64 + cA0 * 8 + bbit * 4] = float2{vr0.x, vr0.y};   \
    *(float2*)&Vs[BUF][(r0) * 64 + cA1 * 8 + bbit * 4] = float2{vr0.z, vr0.w};   \
    *(float2*)&Vs[BUF][(r0 + 32) * 64 + cA0 * 8 + bbit * 4] = float2{vr1.x, vr1.y}; \
    *(float2*)&Vs[BUF][(r0 + 32) * 64 + cA1 * 8 + bbit * 4] = float2{vr1.z, vr1.w};

    FA_LOAD(0);
    FA_WRITE(0);
    __syncthreads();

    f32x4 o[2][4] = {};
    float lsum[2] = {0.f, 0.f};

    for (int it = 0; it < 32; ++it) {
        int buf = it & 1;
        if (it + 1 < 32) { FA_LOAD((it + 1) * 64); }   // issue early; hides under compute

        const __bf16* KsB = &Ks[buf][0];
        const __bf16* VsB = &Vs[buf][0];

        // S^T = K Q^T : st[n][m], lane holds P[q=m*16+lm][kv=16n+4lk+r]
        f32x4 st[4][2] = {};
        __builtin_amdgcn_s_setprio(1);
#pragma unroll
        for (int kk = 0; kk < 2; ++kk) {
            bf16x8 kf[4];
#pragma unroll
            for (int n = 0; n < 4; ++n)
                kf[n] = *(const bf16x8*)&KsB[(n * 16 + lm) * 64 + (((kk * 4 + lk) ^ (lm & 7)) * 8)];
#pragma unroll
            for (int n = 0; n < 4; ++n)
#pragma unroll
                for (int m = 0; m < 2; ++m)
                    st[n][m] = __builtin_amdgcn_mfma_f32_16x16x32_bf16(kf[n], qf[m][kk], st[n][m], 0, 0, 0);
        }
        __builtin_amdgcn_s_setprio(0);

        // P = exp2(S); per-lane row-sum partials (q = m*16+lm fixed per lane)
#pragma unroll
        for (int n = 0; n < 4; ++n)
#pragma unroll
            for (int m = 0; m < 2; ++m)
#pragma unroll
                for (int r = 0; r < 4; ++r) {
                    float p = exp2f(st[n][m][r]);
                    lsum[m] += p;
                    st[n][m][r] = p;
                }

        // O += P V under kv-permutation pi: pa assembled lane-locally; V pre-permuted in LDS
        __builtin_amdgcn_s_setprio(1);
#pragma unroll
        for (int kk = 0; kk < 2; ++kk) {
            bf16x8 pa[2], vf[4];
#pragma unroll
            for (int m = 0; m < 2; ++m)
#pragma unroll
                for (int j = 0; j < 8; ++j)
                    pa[m][j] = (__bf16)st[2 * kk + (j >> 2)][m][j & 3];
#pragma unroll
            for (int dn = 0; dn < 4; ++dn)
                vf[dn] = *(const bf16x8*)&VsB[(dn * 16 + lm) * 64 + (((kk * 4 + lk) ^ (lm & 7)) * 8)];
#pragma unroll
            for (int m = 0; m < 2; ++m)
#pragma unroll
                for (int dn = 0; dn < 4; ++dn)
                    o[m][dn] = __builtin_amdgcn_mfma_f32_16x16x32_bf16(pa[m], vf[dn], o[m][dn], 0, 0, 0);
        }
        __builtin_amdgcn_s_setprio(0);

        if (it + 1 < 32) { FA_WRITE(buf ^ 1); }        // lands in the other buffer
        __syncthreads();                               // one barrier per tile
    }

    // row sums: reduce over the 4 lk lanes, redistribute via tiny LDS (once per kernel)
#pragma unroll
    for (int m = 0; m < 2; ++m) {
        lsum[m] += __shfl_xor(lsum[m], 16);
        lsum[m] += __shfl_xor(lsum[m], 32);
        lsq[w][m * 16 + lm] = lsum[m];
    }
    __syncthreads();
    float inv[2][4];
#pragma unroll
    for (int m = 0; m < 2; ++m)
#pragma unroll
        for (int r = 0; r < 4; ++r)
            inv[m][r] = 1.f / lsq[w][m * 16 + lk * 4 + r];
#pragma unroll
    for (int m = 0; m < 2; ++m)
#pragma unroll
        for (int dn = 0; dn < 4; ++dn)
#pragma unroll
            for (int r = 0; r < 4; ++r) {
                int row = q0 + w * 32 + m * 16 + lk * 4 + r;
                int col = h * HS + dn * 16 + lm;
                O[(size_t)(b * SQ + row) * DD + col] = (__bf16)(o[m][dn][r] * inv[m][r]);
            }
}

extern "C" void kernel_launch(void* const* d_in, const int* in_sizes, int n_in,
                              void* d_out, int out_size, void* d_ws, size_t ws_size,
                              hipStream_t stream) {
    const float* inputs  = (const float*)d_in[0];
    const float* context = (const float*)d_in[1];
    const float* Wq = (const float*)d_in[2];
    const float* bq = (const float*)d_in[3];
    const float* Wk = (const float*)d_in[4];
    const float* bk = (const float*)d_in[5];
    const float* Wv = (const float*)d_in[6];
    const float* bv = (const float*)d_in[7];
    const float* Wo = (const float*)d_in[8];
    const float* bo = (const float*)d_in[9];
    float* out = (float*)d_out;

    char* ws = (char*)d_ws;
    const size_t SEG = (size_t)4096 * 1024 * sizeof(__bf16);  // 8 MB
    __bf16* inA  = (__bf16*)(ws + 0 * SEG);
    __bf16* ctxB = (__bf16*)(ws + 1 * SEG);
    __bf16* Wt   = (__bf16*)(ws + 2 * SEG);   // 4 x 1024x1024 bf16
    __bf16* Qb   = (__bf16*)(ws + 3 * SEG);
    __bf16* Kbuf = (__bf16*)(ws + 4 * SEG);
    __bf16* Vtb  = (__bf16*)(ws + 5 * SEG);   // V written directly transposed by gemm_qkv
    __bf16* attb = ctxB;                      // context_bf16 dead after QKV GEMM

    int n8 = 4096 * 1024 / 8;
    cast2_f32_bf16<<<2 * n8 / 256, 256, 0, stream>>>(inputs, context, inA, ctxB, n8);
    wtrans<<<dim3(32, 32, 4), dim3(32, 8), 0, stream>>>(Wq, Wk, Wv, Wo, Wt);

    gemm_qkv<<<dim3(8, 32, 3), 256, 0, stream>>>(inA, ctxB, Wt, bq, bk, bv,
                                                 Qb, Kbuf, Vtb, SCALE * LOG2E);

    flash_attn<<<dim3(16, 32), 256, 0, stream>>>(Qb, Kbuf, Vtb, attb);

    gemm_out<<<dim3(8, 32), 256, 0, stream>>>(attb, Wt + (size_t)3 * DD * DD, bo, out);
}